// Round 1
// baseline (433.069 us; speedup 1.0000x reference)
//
#include <hip/hip_runtime.h>

#define BATCH 4
#define CCH 512
#define NPIX 4096
#define NGRP 32
#define GSZ 16
#define GN_EPS 1e-6f

typedef __attribute__((ext_vector_type(8))) short short8;
typedef __attribute__((ext_vector_type(8))) unsigned short ushort8;
typedef __attribute__((ext_vector_type(4))) unsigned short ushort4v;
typedef __attribute__((ext_vector_type(4))) float f32x4;

__device__ inline unsigned short f2bf(float f) {
  unsigned u = __float_as_uint(f);
  unsigned r = u + 0x7fffu + ((u >> 16) & 1u);
  return (unsigned short)(r >> 16);
}

// ---------------- GroupNorm stats: one block per (b, group) ----------------
__global__ __launch_bounds__(256) void gn_stats(const float* __restrict__ x,
                                                float* __restrict__ stats) {
  int bg = blockIdx.x;  // b*32 + g ; group data is contiguous 16*4096 floats
  const f32x4* base = (const f32x4*)(x + (size_t)bg * (GSZ * NPIX));
  float s = 0.f, ss = 0.f;
  const int n4 = GSZ * NPIX / 4;  // 16384
  for (int i = threadIdx.x; i < n4; i += 256) {
    f32x4 v = base[i];
    s += v.x + v.y + v.z + v.w;
    ss += v.x * v.x + v.y * v.y + v.z * v.z + v.w * v.w;
  }
  for (int off = 32; off > 0; off >>= 1) {
    s += __shfl_xor(s, off, 64);
    ss += __shfl_xor(ss, off, 64);
  }
  __shared__ float rs[4], rss[4];
  int lane = threadIdx.x & 63, wid = threadIdx.x >> 6;
  if (lane == 0) { rs[wid] = s; rss[wid] = ss; }
  __syncthreads();
  if (threadIdx.x == 0) {
    float S = rs[0] + rs[1] + rs[2] + rs[3];
    float SS = rss[0] + rss[1] + rss[2] + rss[3];
    const float inv = 1.f / (float)(GSZ * NPIX);
    float mean = S * inv;
    float var = SS * inv - mean * mean;
    stats[bg * 2] = mean;
    stats[bg * 2 + 1] = rsqrtf(var + GN_EPS);
  }
}

// ------- GN apply + transpose: x (b,c,n) f32 -> hT (b,n,c) bf16 ----------
__global__ __launch_bounds__(256) void gn_apply_t(const float* __restrict__ x,
                                                  const float* __restrict__ stats,
                                                  const float* __restrict__ gw,
                                                  const float* __restrict__ gb,
                                                  unsigned short* __restrict__ hT) {
  __shared__ float tile[64][65];
  int b = blockIdx.z, c0 = blockIdx.y * 64, n0 = blockIdx.x * 64;
  int t = threadIdx.x;
  int tc4 = t & 15, tr = t >> 4;
  const float* xb = x + ((size_t)b * CCH + c0) * NPIX + n0;
#pragma unroll
  for (int j = 0; j < 4; ++j) {
    int row = tr + j * 16;
    int c = c0 + row;
    float mean = stats[((size_t)b * NGRP + (c >> 4)) * 2];
    float rstd = stats[((size_t)b * NGRP + (c >> 4)) * 2 + 1];
    float ga = gw[c] * rstd;
    float be = gb[c] - mean * ga;
    f32x4 v = *(const f32x4*)(xb + (size_t)row * NPIX + tc4 * 4);
    tile[row][tc4 * 4 + 0] = v.x * ga + be;
    tile[row][tc4 * 4 + 1] = v.y * ga + be;
    tile[row][tc4 * 4 + 2] = v.z * ga + be;
    tile[row][tc4 * 4 + 3] = v.w * ga + be;
  }
  __syncthreads();
  int cc = t & 7, nr = t >> 3;
  unsigned short* outp = hT + ((size_t)b * NPIX + n0) * CCH + c0;
#pragma unroll
  for (int j = 0; j < 2; ++j) {
    int n = nr + j * 32;
    ushort8 pk;
#pragma unroll
    for (int i = 0; i < 8; ++i) pk[i] = f2bf(tile[cc * 8 + i][n]);
    *(ushort8*)(outp + (size_t)n * CCH + cc * 8) = pk;
  }
}

// ---------------- fp32 -> bf16 weight conversion ----------------
__global__ __launch_bounds__(256) void f32_to_bf16(const float* __restrict__ src,
                                                   unsigned short* __restrict__ dst,
                                                   int n4) {
  int i = blockIdx.x * 256 + threadIdx.x;
  if (i < n4) {
    f32x4 v = ((const f32x4*)src)[i];
    ushort4v o;
    o.x = f2bf(v.x); o.y = f2bf(v.y); o.z = f2bf(v.z); o.w = f2bf(v.w);
    ((ushort4v*)dst)[i] = o;
  }
}

// ---------------- B^T GEMM: C[M,N] = A(M,K) . B(N,K)^T ----------------
// 128x128 tile, 4 waves (2x2), each wave 64x64 via 4x4 16x16x32 bf16 MFMA.
// BIAS_MODE: 0 none, 1 bias[row], 2 bias[col]. OUT_BF16: 1 -> ushort out.
// RESID: add resid[row*ldc+col] (fp32).
template <int BIAS_MODE, int OUT_BF16, int RESID>
__global__ __launch_bounds__(256, 2) void gemm_bt(
    const unsigned short* __restrict__ A, const unsigned short* __restrict__ B,
    void* __restrict__ Cv, const float* __restrict__ bias,
    const float* __restrict__ resid, int M, int N, int K, int lda, int ldb,
    int ldc, long sA, long sB, long sC, long sR, float scale) {
  __shared__ __align__(16) unsigned short lA[128][40];  // 32 data + 8 pad (80B rows)
  __shared__ __align__(16) unsigned short lB[128][40];
  const int t = threadIdx.x;
  const int lane = t & 63, wid = t >> 6;
  const int wr = wid >> 1, wc = wid & 1;
  const int fr = lane & 15, kg = lane >> 4;
  const int m0 = blockIdx.x * 128, n0 = blockIdx.y * 128;
  const long bz = blockIdx.z;
  const unsigned short* Ab = A + bz * sA;
  const unsigned short* Bb = B + bz * sB;
  const int srow = t >> 1, skc = (t & 1) * 16;
  const unsigned short* gA = Ab + (size_t)(m0 + srow) * lda + skc;
  const unsigned short* gB = Bb + (size_t)(n0 + srow) * ldb + skc;

  short8 pa0 = *(const short8*)(gA);
  short8 pa1 = *(const short8*)(gA + 8);
  short8 pb0 = *(const short8*)(gB);
  short8 pb1 = *(const short8*)(gB + 8);

  f32x4 acc[4][4];
  const f32x4 zero = {0.f, 0.f, 0.f, 0.f};
#pragma unroll
  for (int m = 0; m < 4; ++m)
#pragma unroll
    for (int n = 0; n < 4; ++n) acc[m][n] = zero;

  for (int k0 = 0; k0 < K; k0 += 32) {
    __syncthreads();
    *(short8*)&lA[srow][skc] = pa0;
    *(short8*)&lA[srow][skc + 8] = pa1;
    *(short8*)&lB[srow][skc] = pb0;
    *(short8*)&lB[srow][skc + 8] = pb1;
    __syncthreads();
    if (k0 + 32 < K) {
      pa0 = *(const short8*)(gA + k0 + 32);
      pa1 = *(const short8*)(gA + k0 + 40);
      pb0 = *(const short8*)(gB + k0 + 32);
      pb1 = *(const short8*)(gB + k0 + 40);
    }
    short8 af[4], bfr[4];
#pragma unroll
    for (int m = 0; m < 4; ++m)
      af[m] = *(const short8*)&lA[wr * 64 + m * 16 + fr][kg * 8];
#pragma unroll
    for (int n = 0; n < 4; ++n)
      bfr[n] = *(const short8*)&lB[wc * 64 + n * 16 + fr][kg * 8];
#pragma unroll
    for (int m = 0; m < 4; ++m)
#pragma unroll
      for (int n = 0; n < 4; ++n)
        acc[m][n] =
            __builtin_amdgcn_mfma_f32_16x16x32_bf16(af[m], bfr[n], acc[m][n], 0, 0, 0);
  }

  // epilogue: C/D layout col = lane&15, row = (lane>>4)*4 + reg  [m89]
  const int rowbase = m0 + wr * 64 + kg * 4;
  const int colbase = n0 + wc * 64 + fr;
#pragma unroll
  for (int m = 0; m < 4; ++m) {
#pragma unroll
    for (int n = 0; n < 4; ++n) {
      int col = colbase + n * 16;
#pragma unroll
      for (int r = 0; r < 4; ++r) {
        int row = rowbase + m * 16 + r;
        float v = acc[m][n][r] * scale;
        if (BIAS_MODE == 1) v += bias[row];
        if (BIAS_MODE == 2) v += bias[col];
        if (RESID) v += resid[(size_t)bz * sR + (size_t)row * ldc + col];
        size_t idx = (size_t)bz * sC + (size_t)row * ldc + col;
        if (OUT_BF16)
          ((unsigned short*)Cv)[idx] = f2bf(v);
        else
          ((float*)Cv)[idx] = v;
      }
    }
  }
}

// ---------------- row softmax: S (4096 f32) -> P (4096 bf16) ----------------
__global__ __launch_bounds__(256) void softmax_rows(const float* __restrict__ S,
                                                    unsigned short* __restrict__ P) {
  const int row = blockIdx.x;
  const int t = threadIdx.x;
  const float* Sr = S + (size_t)row * NPIX;
  f32x4 v[4];
  float mx = -3.4e38f;
#pragma unroll
  for (int j = 0; j < 4; ++j) {
    v[j] = *(const f32x4*)(Sr + j * 1024 + t * 4);
    mx = fmaxf(mx, fmaxf(fmaxf(v[j].x, v[j].y), fmaxf(v[j].z, v[j].w)));
  }
  for (int off = 32; off > 0; off >>= 1) mx = fmaxf(mx, __shfl_xor(mx, off, 64));
  __shared__ float r1[4], r2[4];
  int lane = t & 63, wid = t >> 6;
  if (lane == 0) r1[wid] = mx;
  __syncthreads();
  mx = fmaxf(fmaxf(r1[0], r1[1]), fmaxf(r1[2], r1[3]));
  float sum = 0.f;
#pragma unroll
  for (int j = 0; j < 4; ++j) {
    v[j].x = __expf(v[j].x - mx);
    v[j].y = __expf(v[j].y - mx);
    v[j].z = __expf(v[j].z - mx);
    v[j].w = __expf(v[j].w - mx);
    sum += v[j].x + v[j].y + v[j].z + v[j].w;
  }
  for (int off = 32; off > 0; off >>= 1) sum += __shfl_xor(sum, off, 64);
  if (lane == 0) r2[wid] = sum;
  __syncthreads();
  float inv = 1.f / (r2[0] + r2[1] + r2[2] + r2[3]);
  unsigned short* Pr = P + (size_t)row * NPIX;
#pragma unroll
  for (int j = 0; j < 4; ++j) {
    ushort4v o;
    o.x = f2bf(v[j].x * inv);
    o.y = f2bf(v[j].y * inv);
    o.z = f2bf(v[j].z * inv);
    o.w = f2bf(v[j].w * inv);
    *(ushort4v*)(Pr + j * 1024 + t * 4) = o;
  }
}

extern "C" void kernel_launch(void* const* d_in, const int* in_sizes, int n_in,
                              void* d_out, int out_size, void* d_ws, size_t ws_size,
                              hipStream_t stream) {
  const float* x = (const float*)d_in[0];
  const float* gnw = (const float*)d_in[1];
  const float* gnb = (const float*)d_in[2];
  const float* wq = (const float*)d_in[3];
  const float* bq = (const float*)d_in[4];
  const float* wk = (const float*)d_in[5];
  const float* bk = (const float*)d_in[6];
  const float* wv = (const float*)d_in[7];
  const float* bv = (const float*)d_in[8];
  const float* wp = (const float*)d_in[9];
  const float* bp = (const float*)d_in[10];
  float* out = (float*)d_out;

  const size_t BS = (size_t)NPIX * CCH;  // 2097152 elems per batch-slab
  // workspace layout (bytes):
  // stats 1KB | hT 16.8M | q 16.8M | kT 16.8M | v 16.8M | Aout 16.8M |
  // S 67.1M (f32, per-batch reuse) | P 67.1M (bf16 x2 batches) | w_bf 2.1M
  const size_t need = 1024 + 5 * BS * 2 * BATCH / 4 * 4  /*see below*/;
  (void)need;
  char* ws = (char*)d_ws;
  float* stats = (float*)ws;
  unsigned short* hT = (unsigned short*)(ws + 1024);
  unsigned short* qb = hT + BATCH * BS;
  unsigned short* kTb = qb + BATCH * BS;
  unsigned short* vb = kTb + BATCH * BS;
  unsigned short* Ab = vb + BATCH * BS;
  float* Sb = (float*)(Ab + BATCH * BS);
  unsigned short* Pb = (unsigned short*)(Sb + (size_t)NPIX * NPIX);
  unsigned short* wqb = Pb + 2 * (size_t)NPIX * NPIX;
  unsigned short* wkb = wqb + CCH * CCH;
  unsigned short* wvb = wkb + CCH * CCH;
  unsigned short* wpb = wvb + CCH * CCH;
  size_t total_bytes = (size_t)((char*)(wpb + CCH * CCH) - ws);
  if (ws_size < total_bytes) return;  // ws too small: distinct failure signal

  f32_to_bf16<<<256, 256, 0, stream>>>(wq, wqb, CCH * CCH / 4);
  f32_to_bf16<<<256, 256, 0, stream>>>(wk, wkb, CCH * CCH / 4);
  f32_to_bf16<<<256, 256, 0, stream>>>(wv, wvb, CCH * CCH / 4);
  f32_to_bf16<<<256, 256, 0, stream>>>(wp, wpb, CCH * CCH / 4);

  gn_stats<<<BATCH * NGRP, 256, 0, stream>>>(x, stats);
  gn_apply_t<<<dim3(NPIX / 64, CCH / 64, BATCH), 256, 0, stream>>>(x, stats, gnw,
                                                                   gnb, hT);

  // q[n,o] = sum_c hT[n,c] wq[o,c] + bq[o]   (bias over col)
  gemm_bt<2, 1, 0><<<dim3(32, 4, BATCH), 256, 0, stream>>>(
      hT, wqb, qb, bq, nullptr, NPIX, CCH, CCH, CCH, CCH, CCH, (long)BS, 0,
      (long)BS, 0, 1.f);
  // kT[m,o] = sum_c hT[m,c] wk[o,c] + bk[o]
  gemm_bt<2, 1, 0><<<dim3(32, 4, BATCH), 256, 0, stream>>>(
      hT, wkb, kTb, bk, nullptr, NPIX, CCH, CCH, CCH, CCH, CCH, (long)BS, 0,
      (long)BS, 0, 1.f);
  // v[c,m] = sum_c' wv[c,c'] hT[m,c'] + bv[c]   (bias over row)
  gemm_bt<1, 1, 0><<<dim3(4, 32, BATCH), 256, 0, stream>>>(
      wvb, hT, vb, bv, nullptr, CCH, NPIX, CCH, CCH, CCH, NPIX, 0, (long)BS,
      (long)BS, 0, 1.f);

  const float sscale = 0.044194173824159216f;  // 512^-0.5
  for (int p = 0; p < 2; ++p) {
    for (int i = 0; i < 2; ++i) {
      int b = p * 2 + i;
      // S[q,m] = scale * sum_o q[q,o] kT[m,o]   (fp32)
      gemm_bt<0, 0, 0><<<dim3(32, 32, 1), 256, 0, stream>>>(
          qb + (size_t)b * BS, kTb + (size_t)b * BS, Sb, nullptr, nullptr, NPIX,
          NPIX, CCH, CCH, CCH, NPIX, 0, 0, 0, 0, sscale);
      softmax_rows<<<NPIX, 256, 0, stream>>>(Sb, Pb + (size_t)i * NPIX * NPIX);
    }
    // AoutT[q,c] = sum_m P[q,m] v[c,m]   for batches 2p, 2p+1
    gemm_bt<0, 1, 0><<<dim3(32, 4, 2), 256, 0, stream>>>(
        Pb, vb + (size_t)p * 2 * BS, Ab + (size_t)p * 2 * BS, nullptr, nullptr,
        NPIX, CCH, NPIX, NPIX, NPIX, CCH, (long)NPIX * NPIX, (long)BS, (long)BS,
        0, 1.f);
  }
  // out[o,n] = sum_c wp[o,c] AoutT[n,c] + bp[o] + x[b,o,n]
  gemm_bt<1, 0, 1><<<dim3(4, 32, BATCH), 256, 0, stream>>>(
      wpb, Ab, out, bp, x, CCH, NPIX, CCH, CCH, CCH, NPIX, 0, (long)BS, (long)BS,
      (long)BS, 1.f);
}